// Round 10
// baseline (710.020 us; speedup 1.0000x reference)
//
#include <hip/hip_runtime.h>

// ---------------------------------------------------------------------------
// Problem constants (B=16, N=128, FIN=D=512)
// ---------------------------------------------------------------------------
#define BATCH 16
#define NNODE 128
#define DIM 512
#define NP1 129              // N+1 (with virtual node)
#define EDSZ (NP1 * NP1)     // 16641 per batch
#define BIGF 3.0e38f         // sentinel (finite)

// ---------------------------------------------------------------------------
// Fused dual-input GEMM (NT): Y{0,1}[m][n] = relu(sum_k X{0,1}[m][k]*W[n][k]+b[n])
// Virtual node rides along as row M (block gridDim.x-1, z==0 only).
// Layer-1 call also zeroes the per-batch fp64 sums (block 0; visible to
// cdist two kernel boundaries later).
// ---------------------------------------------------------------------------
__global__ __launch_bounds__(256) void gemm2_nt_relu(
    const float* __restrict__ X0, const float* __restrict__ X1,
    const float* __restrict__ VS,   // virtual-source row (K floats)
    const float* __restrict__ W, const float* __restrict__ bias,
    float* __restrict__ Y0, float* __restrict__ Y1,
    double* sums0,                  // if non-null: zeroed by block (0,0,0)
    int M, int N, int K) {
  if (blockIdx.x == gridDim.x - 1 && blockIdx.z) return;  // virtual tile: z==0 only
  if (sums0 && blockIdx.x == 0 && blockIdx.y == 0 && blockIdx.z == 0 &&
      threadIdx.x < BATCH)
    sums0[threadIdx.x] = 0.0;
  const float* X = blockIdx.z ? X1 : X0;
  float* Y = blockIdx.z ? Y1 : Y0;
  __shared__ float sA[32][68];
  __shared__ float sB[32][68];
  const int tid = threadIdx.x;
  const int m0 = blockIdx.x * 64;
  const int n0 = blockIdx.y * 64;
  const int tm = tid / 16, tn = tid % 16;
  const int lr = tid >> 2;
  const int lk8 = (tid & 3) * 8;
  const int row = m0 + lr;
  const float* xrow = (row < M) ? (X + (size_t)row * K) : VS;
  const float* wrow = W + (size_t)(n0 + lr) * K;
  float acc[4][4] = {};
  for (int k0 = 0; k0 < K; k0 += 32) {
    const float* xa = xrow + k0 + lk8;
    const float* wb = wrow + k0 + lk8;
    float4 a0 = *(const float4*)(xa);
    float4 a1 = *(const float4*)(xa + 4);
    float4 b0 = *(const float4*)(wb);
    float4 b1 = *(const float4*)(wb + 4);
    sA[lk8 + 0][lr] = a0.x; sA[lk8 + 1][lr] = a0.y;
    sA[lk8 + 2][lr] = a0.z; sA[lk8 + 3][lr] = a0.w;
    sA[lk8 + 4][lr] = a1.x; sA[lk8 + 5][lr] = a1.y;
    sA[lk8 + 6][lr] = a1.z; sA[lk8 + 7][lr] = a1.w;
    sB[lk8 + 0][lr] = b0.x; sB[lk8 + 1][lr] = b0.y;
    sB[lk8 + 2][lr] = b0.z; sB[lk8 + 3][lr] = b0.w;
    sB[lk8 + 4][lr] = b1.x; sB[lk8 + 5][lr] = b1.y;
    sB[lk8 + 6][lr] = b1.z; sB[lk8 + 7][lr] = b1.w;
    __syncthreads();
#pragma unroll
    for (int k = 0; k < 32; ++k) {
      const float4 a = *(const float4*)&sA[k][tm * 4];
      const float4 b = *(const float4*)&sB[k][tn * 4];
      acc[0][0] = fmaf(a.x, b.x, acc[0][0]);
      acc[0][1] = fmaf(a.x, b.y, acc[0][1]);
      acc[0][2] = fmaf(a.x, b.z, acc[0][2]);
      acc[0][3] = fmaf(a.x, b.w, acc[0][3]);
      acc[1][0] = fmaf(a.y, b.x, acc[1][0]);
      acc[1][1] = fmaf(a.y, b.y, acc[1][1]);
      acc[1][2] = fmaf(a.y, b.z, acc[1][2]);
      acc[1][3] = fmaf(a.y, b.w, acc[1][3]);
      acc[2][0] = fmaf(a.z, b.x, acc[2][0]);
      acc[2][1] = fmaf(a.z, b.y, acc[2][1]);
      acc[2][2] = fmaf(a.z, b.z, acc[2][2]);
      acc[2][3] = fmaf(a.z, b.w, acc[2][3]);
      acc[3][0] = fmaf(a.w, b.x, acc[3][0]);
      acc[3][1] = fmaf(a.w, b.y, acc[3][1]);
      acc[3][2] = fmaf(a.w, b.z, acc[3][2]);
      acc[3][3] = fmaf(a.w, b.w, acc[3][3]);
    }
    __syncthreads();
  }
#pragma unroll
  for (int i = 0; i < 4; ++i) {
    int m = m0 + tm * 4 + i;
#pragma unroll
    for (int j = 0; j < 4; ++j) {
      int n = n0 + tn * 4 + j;
      if (m <= M)  // rows beyond the virtual row are scratch work
        Y[(size_t)m * N + n] = fmaxf(acc[i][j] + bias[n], 0.f);
    }
  }
}

// ---------------------------------------------------------------------------
// cdist: d[b][i][j] = || esrow(b,i) - etrow(b,j) ||_2
// Also accumulates per-batch fp64 sum via atomicAdd (validated R21/R22).
// R24: LDS traffic vectorized — stride-36 rows (144B, 16B-aligned) so both
// staging (2x ds_write_b128, was 8x b32) and the inner loop (4x ds_read_b128
// per 4-k group, was 16x b32) are 16B ops: 4x fewer LDS instructions (this
// kernel was LDS-instruction-bound at 2:1 VALU:LDS; now 8:1). Reads
// broadcast within 16-lane groups (same row) — no new conflicts. FMA order
// per accumulator is exactly k=0..31 as before -> d is BIT-IDENTICAL.
// ---------------------------------------------------------------------------
__global__ __launch_bounds__(256) void cdist_kernel(
    const float* __restrict__ es, const float* __restrict__ et,
    const float* __restrict__ ev, float* __restrict__ d,
    double* __restrict__ sums_d) {
  const int b = blockIdx.z;
  const int i0 = blockIdx.x * 32;
  const int j0 = blockIdx.y * 32;
  __shared__ float sA[32][36];
  __shared__ float sB[32][36];
  const int tid = threadIdx.x;
  const int ty = tid / 16, tx = tid % 16;
  const int lr = tid / 8;
  const int lk4 = (tid % 8) * 4;
  const int gi = i0 + lr;
  const int gj = j0 + lr;
  const float* pa = (gi < NNODE) ? (es + ((size_t)b * NNODE + gi) * DIM) : ev;
  const float* pb = (gj < NNODE) ? (et + ((size_t)b * NNODE + gj) * DIM) : ev;
  float acc[2][2] = {};
  for (int k0 = 0; k0 < DIM; k0 += 32) {
    float4 av = *(const float4*)(pa + k0 + lk4);
    float4 bv = *(const float4*)(pb + k0 + lk4);
    *(float4*)&sA[lr][lk4] = av;
    *(float4*)&sB[lr][lk4] = bv;
    __syncthreads();
#pragma unroll
    for (int k = 0; k < 32; k += 4) {
      const float4 a0q = *(const float4*)&sA[ty * 2 + 0][k];
      const float4 a1q = *(const float4*)&sA[ty * 2 + 1][k];
      const float4 b0q = *(const float4*)&sB[tx * 2 + 0][k];
      const float4 b1q = *(const float4*)&sB[tx * 2 + 1][k];
      // component-by-component in k order => identical FMA sequence
      {
        float d00 = a0q.x - b0q.x, d01 = a0q.x - b1q.x;
        float d10 = a1q.x - b0q.x, d11 = a1q.x - b1q.x;
        acc[0][0] = fmaf(d00, d00, acc[0][0]);
        acc[0][1] = fmaf(d01, d01, acc[0][1]);
        acc[1][0] = fmaf(d10, d10, acc[1][0]);
        acc[1][1] = fmaf(d11, d11, acc[1][1]);
      }
      {
        float d00 = a0q.y - b0q.y, d01 = a0q.y - b1q.y;
        float d10 = a1q.y - b0q.y, d11 = a1q.y - b1q.y;
        acc[0][0] = fmaf(d00, d00, acc[0][0]);
        acc[0][1] = fmaf(d01, d01, acc[0][1]);
        acc[1][0] = fmaf(d10, d10, acc[1][0]);
        acc[1][1] = fmaf(d11, d11, acc[1][1]);
      }
      {
        float d00 = a0q.z - b0q.z, d01 = a0q.z - b1q.z;
        float d10 = a1q.z - b0q.z, d11 = a1q.z - b1q.z;
        acc[0][0] = fmaf(d00, d00, acc[0][0]);
        acc[0][1] = fmaf(d01, d01, acc[0][1]);
        acc[1][0] = fmaf(d10, d10, acc[1][0]);
        acc[1][1] = fmaf(d11, d11, acc[1][1]);
      }
      {
        float d00 = a0q.w - b0q.w, d01 = a0q.w - b1q.w;
        float d10 = a1q.w - b0q.w, d11 = a1q.w - b1q.w;
        acc[0][0] = fmaf(d00, d00, acc[0][0]);
        acc[0][1] = fmaf(d01, d01, acc[0][1]);
        acc[1][0] = fmaf(d10, d10, acc[1][0]);
        acc[1][1] = fmaf(d11, d11, acc[1][1]);
      }
    }
    __syncthreads();
  }
  double psum = 0.0;
#pragma unroll
  for (int i = 0; i < 2; ++i) {
    int gi2 = i0 + ty * 2 + i;
#pragma unroll
    for (int j = 0; j < 2; ++j) {
      int gj2 = j0 + tx * 2 + j;
      if (gi2 < NP1 && gj2 < NP1) {
        const float s = sqrtf(acc[i][j]);
        d[(size_t)b * EDSZ + gi2 * NP1 + gj2] = s;
        psum += (double)s;
      }
    }
  }
  // per-wave reduce, one fp64 atomic per wave (4/block)
#pragma unroll
  for (int off = 32; off; off >>= 1) psum += __shfl_xor(psum, off);
  if ((tid & 63) == 0) atomicAdd(&sums_d[b], psum);
}

// ---------------------------------------------------------------------------
// Parallel normalize + A-zero (replaces sum_normalize AND the memset).
// Same per-element expression as the validated normalize:
// e = d / sumf * 16384.f.
// ---------------------------------------------------------------------------
__global__ __launch_bounds__(256) void normalize_zero(
    const float* __restrict__ d, const double* __restrict__ sums_d,
    float* __restrict__ edit, float* __restrict__ Aout) {
  const int b = blockIdx.x;
  const float sumf = (float)sums_d[b];
  const float nn = (float)(NNODE * NNODE);
  const float* db = d + (size_t)b * EDSZ;
  float* eb = edit + (size_t)b * EDSZ;
  float* Ab = Aout + (size_t)b * EDSZ;
  for (int idx = blockIdx.y * 256 + threadIdx.x; idx < EDSZ;
       idx += 256 * gridDim.y) {
    eb[idx] = db[idx] / sumf * nn;
    Ab[idx] = 0.f;
  }
}

// ---------------------------------------------------------------------------
// cross-lane helpers: 32-bit packed argmin on the VALU pipe.
// key = (f32 bits of nonneg value with low 7 mantissa bits replaced by col).
// Unsigned order == value order (to within 2^-17 rel; ties -> lowest col).
// Exact values recovered by readlane from the winner lane.
//
// Wave-min: the 6-step builtin update_dpp chain, FINAL. Three attempts to
// beat it all lost:
//   R14 hand-fused v_min_u32_dpp asm -> VALU->DPP hazard violation, hang.
//   R16 asm + embedded s_nop -> +49us (forced nops + asm sched barriers).
//   R22 readlane-tail (4 readlane + s_min tree) -> +18us (readlane-after-
//        VALU wait states + SALU chain beat by DPP's hazard-filled slots).
// Do not touch this function again.
// ---------------------------------------------------------------------------
__device__ __forceinline__ unsigned key_of(float m, int col) {
  return (__float_as_uint(m) & 0xFFFFFF80u) | (unsigned)col;
}

__device__ __forceinline__ float readlane_f32(float x, int lane) {
  return __uint_as_float(
      (unsigned)__builtin_amdgcn_readlane((int)__float_as_uint(x), lane));
}

template <int CTRL>
__device__ __forceinline__ unsigned dpp_umin_step(unsigned x) {
  const unsigned o = (unsigned)__builtin_amdgcn_update_dpp(
      (int)0xFFFFFFFFu, (int)x, CTRL, 0xf, 0xf, false);
  return o < x ? o : x;
}

// wave64 min-key; result broadcast (readlane 63).
__device__ __forceinline__ unsigned wave_umin_key(unsigned x) {
  x = dpp_umin_step<0x111>(x);
  x = dpp_umin_step<0x112>(x);
  x = dpp_umin_step<0x114>(x);
  x = dpp_umin_step<0x118>(x);
  x = dpp_umin_step<0x142>(x);
  x = dpp_umin_step<0x143>(x);
  return (unsigned)__builtin_amdgcn_readlane((int)x, 63);
}

// merged (min1,min2) reduction: one DPP chain carries a sorted pair (ARR).
template <int CTRL>
__device__ __forceinline__ void dpp_umin2_step(unsigned& m1, unsigned& m2) {
  const unsigned o1 = (unsigned)__builtin_amdgcn_update_dpp(
      (int)0xFFFFFFFFu, (int)m1, CTRL, 0xf, 0xf, false);
  const unsigned o2 = (unsigned)__builtin_amdgcn_update_dpp(
      (int)0xFFFFFFFFu, (int)m2, CTRL, 0xf, 0xf, false);
  const unsigned lo = m1 < o1 ? m1 : o1;
  const unsigned hi = m1 < o1 ? o1 : m1;
  const unsigned yo = m2 < o2 ? m2 : o2;
  m1 = lo;
  m2 = hi < yo ? hi : yo;
}

__device__ __forceinline__ void wave_umin2_key(unsigned a, unsigned b,
                                               unsigned& k1, unsigned& k2) {
  unsigned m1 = a < b ? a : b;
  unsigned m2 = a < b ? b : a;
  dpp_umin2_step<0x111>(m1, m2);
  dpp_umin2_step<0x112>(m1, m2);
  dpp_umin2_step<0x114>(m1, m2);
  dpp_umin2_step<0x118>(m1, m2);
  dpp_umin2_step<0x142>(m1, m2);
  dpp_umin2_step<0x143>(m1, m2);
  k1 = (unsigned)__builtin_amdgcn_readlane((int)m1, 63);
  k2 = (unsigned)__builtin_amdgcn_readlane((int)m2, 63);
}

// Broadcast element idx of a 128-entry distributed array (2 per lane).
__device__ __forceinline__ float bcast_pair_f(float a0, float a1, int idx) {
  const int l = idx >> 1;
  const float xa = readlane_f32(a0, l);
  const float xb = readlane_f32(a1, l);
  return (idx & 1) ? xb : xa;
}
__device__ __forceinline__ int bcast_pair_i(int a0, int a1, int idx) {
  const int l = idx >> 1;
  const int xa = __builtin_amdgcn_readlane(a0, l);
  const int xb = __builtin_amdgcn_readlane(a1, l);
  return (idx & 1) ? xb : xa;
}

// ---------------------------------------------------------------------------
// LSAPE collapsed to a dense 128x128 LSAP, LAPJV pipeline. ONE WAVE per
// batch, lane owns 2 columns. R20-validated kernel VERBATIM (497us):
// stage D with fminf only, 6-step DPP argmin, col reduction -> greedy ->
// reduction transfer -> adaptive multi-pass ARR -> exact SAP. Scan schedule
// is compiler-optimal (R15/R16/R22); the only lever that has ever moved
// this kernel is SCAN COUNT (R17, R20). GOLDEN — do not touch.
// ---------------------------------------------------------------------------
__global__ __launch_bounds__(64) void lsap_kernel(
    const float* __restrict__ edit, float* __restrict__ Aout,
    float* __restrict__ geds) {
  const int b = blockIdx.x;
  const float* ec = edit + (size_t)b * EDSZ;
  float* A = Aout + (size_t)b * EDSZ;
  const int lane = threadIdx.x;
  const int cbase = lane * 2;  // first owned column (0-based), 2 per lane

  __shared__ float D[NNODE * NNODE];  // 64 KB dense collapsed cost

  // stage D = min(sub, del+ins); coalesced global reads (L2-resident)
  for (int idx = lane; idx < NNODE * NNODE; idx += 64) {
    const int i = idx >> 7, j = idx & 127;
    const float sub = ec[i * NP1 + j];
    const float di = ec[i * NP1 + NNODE] + ec[NNODE * NP1 + j];
    D[idx] = fminf(sub, di);
  }
  __syncthreads();

  const float* Dl = D + cbase;  // lane-local column-pair base

  // per-lane state: 2 columns (v, minv, way, p) + 2 rows (u, x=row->col+1)
  float u0 = 0.f, u1 = 0.f;
  float v0 = 0.f, v1 = 0.f;
  float m0, m1;
  int w0 = 0, w1 = 0;
  int p0 = 0, p1 = 0;
  int x0 = 0, x1 = 0;

  // ---------------- Phase 1: column reduction on dense D ----------------
  int y0 = 0, y1 = 0;
  {
    float c0 = BIGF, c1 = BIGF;
    for (int r = 0; r < NNODE; ++r) {
      const float2 f = *(const float2*)(Dl + (r << 7));
      if (f.x < c0) { c0 = f.x; y0 = r; }
      if (f.y < c1) { c1 = f.y; y1 = r; }
    }
    v0 = c0; v1 = c1;
  }

  // Greedy conflict-free assignment (wave-uniform scalar walk over columns).
  unsigned long long ra0 = 0, ra1 = 0;  // assigned-row bits (0..63, 64..127)
  for (int j = 0; j < NNODE; ++j) {
    const int i1 = bcast_pair_i(y0, y1, j);
    const int bit = i1 & 63;
    const unsigned long long msk = (i1 < 64) ? ra0 : ra1;
    if (!((msk >> bit) & 1ull)) {
      if (i1 < 64) ra0 |= 1ull << bit; else ra1 |= 1ull << bit;
      const bool oj = lane == (j >> 1);
      p0 = (oj && !(j & 1)) ? i1 + 1 : p0;
      p1 = (oj &&  (j & 1)) ? i1 + 1 : p1;
      const bool oi = lane == (i1 >> 1);
      x0 = (oi && !(i1 & 1)) ? j + 1 : x0;
      x1 = (oi &&  (i1 & 1)) ? j + 1 : x1;
    }
  }

  // ---------------- Phase 1r: reduction transfer ----------------
  for (int ii = 0; ii < NNODE; ++ii) {
    const float2 f = *(const float2*)(Dl + (ii << 7));
    const int xj = bcast_pair_i(x0, x1, ii);
    if (xj == 0) continue;
    const int j1 = xj - 1;
    float r0 = fmaxf(f.x - v0, 0.f);
    float r1 = fmaxf(f.y - v1, 0.f);
    if (cbase + 0 == j1) r0 = BIGF;
    if (cbase + 1 == j1) r1 = BIGF;
    const unsigned ka = key_of(r0, cbase + 0);
    const unsigned kb = key_of(r1, cbase + 1);
    const unsigned kmin = wave_umin_key(ka < kb ? ka : kb);
    const int jm = (int)(kmin & 127u);
    const float umin = bcast_pair_f(r0, r1, jm);
    const bool ov = lane == (j1 >> 1);
    v0 = (ov && !(j1 & 1)) ? v0 - umin : v0;
    v1 = (ov &&  (j1 & 1)) ? v1 - umin : v1;
    const bool ou = lane == (ii >> 1);
    u0 = (ou && !(ii & 1)) ? umin : u0;
    u1 = (ou &&  (ii & 1)) ? umin : u1;
  }

  // ---------------- Phase 1.5: adaptive multi-pass ARR ----------------
  // Ordered passes over the pass-start free list; displaced rows wait for
  // the next pass, keep their duals. Stop when a pass converts nothing
  // net, cap 8 passes. (R20 win: ARR step ~400cy vs phase-2 row ~40k cy.)
  {
    int nfree_prev =
        NNODE - __builtin_popcountll(ra0) - __builtin_popcountll(ra1);
    for (int pass = 0; pass < 8 && nfree_prev; ++pass) {
      unsigned long long todo0 = ~ra0, todo1 = ~ra1;
      while (todo0 | todo1) {
        int i;
        if (todo0) { i = __builtin_ctzll(todo0); todo0 &= todo0 - 1ull; }
        else       { i = 64 + __builtin_ctzll(todo1); todo1 &= todo1 - 1ull; }

        const float2 f = *(const float2*)(Dl + (i << 7));
        const float r0 = fmaxf(f.x - v0, 0.f);
        const float r1 = fmaxf(f.y - v1, 0.f);
        unsigned k1, k2;
        wave_umin2_key(key_of(r0, cbase + 0), key_of(r1, cbase + 1), k1, k2);
        const int j1 = (int)(k1 & 127u), j2 = (int)(k2 & 127u);
        const float u1v = bcast_pair_f(r0, r1, j1);
        const float u2v = bcast_pair_f(r0, r1, j2);

        int jt = j1;
        int i1 = bcast_pair_i(p0, p1, j1);
        if (u1v < u2v) {
          const float dv = u2v - u1v;
          const bool ov = lane == (j1 >> 1);
          v0 = (ov && !(j1 & 1)) ? v0 - dv : v0;
          v1 = (ov &&  (j1 & 1)) ? v1 - dv : v1;
        } else if (i1 != 0) {
          jt = j2;
          i1 = bcast_pair_i(p0, p1, j2);
        }
        // assign i -> jt with exact u[i] = u2v (feasible + tight)
        {
          const bool oj = lane == (jt >> 1);
          p0 = (oj && !(jt & 1)) ? i + 1 : p0;
          p1 = (oj &&  (jt & 1)) ? i + 1 : p1;
          const bool oi = lane == (i >> 1);
          u0 = (oi && !(i & 1)) ? u2v : u0;
          u1 = (oi &&  (i & 1)) ? u2v : u1;
        }
        if (i < 64) ra0 |= 1ull << i; else ra1 |= 1ull << (i - 64);
        if (i1 != 0) {
          const int rr = i1 - 1;
          if (rr < 64) ra0 &= ~(1ull << rr); else ra1 &= ~(1ull << (rr - 64));
          // displaced row KEEPS its dual u (feasible: v only decreases)
        }
      }
      const int nfree_now =
          NNODE - __builtin_popcountll(ra0) - __builtin_popcountll(ra1);
      if (nfree_now == nfree_prev) break;  // pass converted nothing net
      nfree_prev = nfree_now;
    }
  }

  // ---------------- Phase 2: SAP for each remaining free row ----------------
  for (int ii = 0; ii < NNODE; ++ii) {
    const unsigned long long amsk = (ii < 64) ? ra0 : ra1;
    if ((amsk >> (ii & 63)) & 1ull) continue;  // assigned in phase 1/1.5
    const int i = ii + 1;

    unsigned cused = 0, rused = 0;
    m0 = m1 = BIGF;
    int j0 = 0;       // current column (0 = dummy start)
    int i0 = i;       // p[0] = i
    for (int guard = 0; guard <= NNODE; ++guard) {
      // --- dense cost row: issue the LDS read first (longest latency) ---
      const float2 f = *(const float2*)(Dl + ((i0 - 1) << 7));

      // --- broadcast u[i0] (parallel readlanes + scalar select) ---
      const float u_i0 = bcast_pair_f(u0, u1, i0 - 1);

      // --- mark used: column j0 (skip dummy col 0) and row i0, branchless ---
      {
        const int jm1 = j0 - 1;
        const bool oc = (j0 > 0) && (lane == (jm1 >> 1));
        const bool c0m = oc && !(jm1 & 1);
        const bool c1m = oc &&  (jm1 & 1);
        cused |= c0m ? 1u : 0u;
        cused |= c1m ? 2u : 0u;
        m0 = c0m ? BIGF : m0;
        m1 = c1m ? BIGF : m1;
        const int im1 = i0 - 1;
        const bool orow = lane == (im1 >> 1);
        rused |= (orow && !(im1 & 1)) ? 1u : 0u;
        rused |= (orow &&  (im1 & 1)) ? 2u : 0u;
      }

      // --- relax free columns; clamp >=0 keeps key ordering sound ---
      {
        const float cur0 = fmaxf(f.x - u_i0 - v0, 0.f);
        const bool up0 = !(cused & 1u) && (cur0 < m0);
        m0 = up0 ? cur0 : m0;
        w0 = up0 ? j0 : w0;
        const float cur1 = fmaxf(f.y - u_i0 - v1, 0.f);
        const bool up1 = !(cused & 2u) && (cur1 < m1);
        m1 = up1 ? cur1 : m1;
        w1 = up1 ? j0 : w1;
      }

      // --- 32-bit key argmin; exact delta via winner readlane ---
      const unsigned ka = key_of(m0, cbase + 0);
      const unsigned kb = key_of(m1, cbase + 1);
      const unsigned kmin = wave_umin_key(ka < kb ? ka : kb);
      const int jcol = (int)(kmin & 127u);
      const float delta = bcast_pair_f(m0, m1, jcol);
      const int pj1 = bcast_pair_i(p0, p1, jcol);

      // --- dual updates (registers only, branchless) ---
      {
        const bool used0 = (cused & 1u) != 0;
        const bool used1 = (cused & 2u) != 0;
        v0 = used0 ? v0 - delta : v0;
        v1 = used1 ? v1 - delta : v1;
        m0 = used0 ? m0 : fmaxf(m0 - delta, 0.f);
        m1 = used1 ? m1 : fmaxf(m1 - delta, 0.f);
        u0 = (rused & 1u) ? u0 + delta : u0;
        u1 = (rused & 2u) ? u1 + delta : u1;
      }

      // --- next (or break on free column) ---
      j0 = jcol + 1;
      if (pj1 == 0) break;
      i0 = pj1;
    }

    // --- augment along way[] chain (uniform walk via readlane) ---
    int jc = j0;
    while (jc != 0) {
      const int jp = bcast_pair_i(w0, w1, jc - 1);
      const int js = (jp == 0) ? 1 : jp;  // safe index for speculative readlane
      const int pvr = bcast_pair_i(p0, p1, js - 1);
      const int pv = (jp == 0) ? i : pvr;
      const bool oc = lane == ((jc - 1) >> 1);
      p0 = (oc && !((jc - 1) & 1)) ? pv : p0;
      p1 = (oc &&  ((jc - 1) & 1)) ? pv : p1;
      jc = jp;
    }
  }

  // --- emit A and geds: column j assigned row p[j+1]-1; re-split branches ---
  double contrib = 0.0;
  {
    const int pr[2] = {p0, p1};
#pragma unroll
    for (int q = 0; q < 2; ++q) {
      const int j = cbase + q;
      const int i = pr[q] - 1;
      const float sub = ec[i * NP1 + j];
      const float di = ec[i * NP1 + NNODE] + ec[NNODE * NP1 + j];
      if (sub < di) {
        A[i * NP1 + j] = 1.f;
        contrib += (double)sub;
      } else {
        A[i * NP1 + NNODE] = 1.f;    // delete row i
        A[NNODE * NP1 + j] = 1.f;    // insert col j
        contrib += (double)di;
      }
    }
  }
#pragma unroll
  for (int off = 32; off; off >>= 1) contrib += __shfl_xor(contrib, off);
  if (lane == 0) geds[b] = (float)(contrib / 256.0);
}

// ---------------------------------------------------------------------------
// launch: 5 dispatches — gemm x2, cdist(+sum), normalize_zero, lsap
// ---------------------------------------------------------------------------
extern "C" void kernel_launch(void* const* d_in, const int* in_sizes, int n_in,
                              void* d_out, int out_size, void* d_ws, size_t ws_size,
                              hipStream_t stream) {
  const float* x_s  = (const float*)d_in[0];
  const float* x_t  = (const float*)d_in[1];
  const float* W1   = (const float*)d_in[2];
  const float* b1   = (const float*)d_in[3];
  const float* W2   = (const float*)d_in[4];
  const float* b2   = (const float*)d_in[5];
  const float* virt = (const float*)d_in[6];

  const int M = BATCH * NNODE;  // 2048

  // h_s / e_s carry one extra row (the virtual node) at index M.
  float* ws    = (float*)d_ws;
  float* h_s   = ws;                                   // (M+1) x DIM
  float* h_t   = h_s + ((size_t)M + 1) * DIM;          //  M    x DIM
  float* e_s   = h_t + (size_t)M * DIM;                // (M+1) x DIM
  float* e_t   = e_s + ((size_t)M + 1) * DIM;          //  M    x DIM
  float* d_raw = e_t + (size_t)M * DIM;                // 16*16641
  double* sums_d = (double*)(d_raw + (size_t)BATCH * EDSZ);  // 16 fp64

  float* Aout = (float*)d_out;
  float* edit = Aout + (size_t)BATCH * EDSZ;
  float* geds = edit + (size_t)BATCH * EDSZ;

  // 33rd x-tile carries the virtual node through both layers (z==0 only)
  dim3 gblk(M / 64 + 1, DIM / 64, 2);  // (33, 8, 2)
  gemm2_nt_relu<<<gblk, 256, 0, stream>>>(x_s, x_t, virt, W1, b1,
                                          h_s, h_t, sums_d, M, DIM, DIM);
  gemm2_nt_relu<<<gblk, 256, 0, stream>>>(h_s, h_t, h_s + (size_t)M * DIM,
                                          W2, b2, e_s, e_t, nullptr,
                                          M, DIM, DIM);

  const float* e_v = e_s + (size_t)M * DIM;
  cdist_kernel<<<dim3(5, 5, BATCH), 256, 0, stream>>>(e_s, e_t, e_v, d_raw,
                                                      sums_d);
  normalize_zero<<<dim3(BATCH, 4), 256, 0, stream>>>(d_raw, sums_d, edit, Aout);
  lsap_kernel<<<BATCH, 64, 0, stream>>>(edit, Aout, geds);
}

// Round 11
// 704.344 us; speedup vs baseline: 1.0081x; 1.0081x over previous
//
#include <hip/hip_runtime.h>

// ---------------------------------------------------------------------------
// Problem constants (B=16, N=128, FIN=D=512)
// ---------------------------------------------------------------------------
#define BATCH 16
#define NNODE 128
#define DIM 512
#define NP1 129              // N+1 (with virtual node)
#define EDSZ (NP1 * NP1)     // 16641 per batch
#define BIGF 3.0e38f         // sentinel (finite)

// ---------------------------------------------------------------------------
// Fused dual-input GEMM (NT): Y{0,1}[m][n] = relu(sum_k X{0,1}[m][k]*W[n][k]+b[n])
// Virtual node rides along as row M (block gridDim.x-1, z==0 only).
// Layer-1 call also zeroes the per-batch fp64 sums (block 0; visible to
// cdist two kernel boundaries later).
// ---------------------------------------------------------------------------
__global__ __launch_bounds__(256) void gemm2_nt_relu(
    const float* __restrict__ X0, const float* __restrict__ X1,
    const float* __restrict__ VS,   // virtual-source row (K floats)
    const float* __restrict__ W, const float* __restrict__ bias,
    float* __restrict__ Y0, float* __restrict__ Y1,
    double* sums0,                  // if non-null: zeroed by block (0,0,0)
    int M, int N, int K) {
  if (blockIdx.x == gridDim.x - 1 && blockIdx.z) return;  // virtual tile: z==0 only
  if (sums0 && blockIdx.x == 0 && blockIdx.y == 0 && blockIdx.z == 0 &&
      threadIdx.x < BATCH)
    sums0[threadIdx.x] = 0.0;
  const float* X = blockIdx.z ? X1 : X0;
  float* Y = blockIdx.z ? Y1 : Y0;
  __shared__ float sA[32][68];
  __shared__ float sB[32][68];
  const int tid = threadIdx.x;
  const int m0 = blockIdx.x * 64;
  const int n0 = blockIdx.y * 64;
  const int tm = tid / 16, tn = tid % 16;
  const int lr = tid >> 2;
  const int lk8 = (tid & 3) * 8;
  const int row = m0 + lr;
  const float* xrow = (row < M) ? (X + (size_t)row * K) : VS;
  const float* wrow = W + (size_t)(n0 + lr) * K;
  float acc[4][4] = {};
  for (int k0 = 0; k0 < K; k0 += 32) {
    const float* xa = xrow + k0 + lk8;
    const float* wb = wrow + k0 + lk8;
    float4 a0 = *(const float4*)(xa);
    float4 a1 = *(const float4*)(xa + 4);
    float4 b0 = *(const float4*)(wb);
    float4 b1 = *(const float4*)(wb + 4);
    sA[lk8 + 0][lr] = a0.x; sA[lk8 + 1][lr] = a0.y;
    sA[lk8 + 2][lr] = a0.z; sA[lk8 + 3][lr] = a0.w;
    sA[lk8 + 4][lr] = a1.x; sA[lk8 + 5][lr] = a1.y;
    sA[lk8 + 6][lr] = a1.z; sA[lk8 + 7][lr] = a1.w;
    sB[lk8 + 0][lr] = b0.x; sB[lk8 + 1][lr] = b0.y;
    sB[lk8 + 2][lr] = b0.z; sB[lk8 + 3][lr] = b0.w;
    sB[lk8 + 4][lr] = b1.x; sB[lk8 + 5][lr] = b1.y;
    sB[lk8 + 6][lr] = b1.z; sB[lk8 + 7][lr] = b1.w;
    __syncthreads();
#pragma unroll
    for (int k = 0; k < 32; ++k) {
      const float4 a = *(const float4*)&sA[k][tm * 4];
      const float4 b = *(const float4*)&sB[k][tn * 4];
      acc[0][0] = fmaf(a.x, b.x, acc[0][0]);
      acc[0][1] = fmaf(a.x, b.y, acc[0][1]);
      acc[0][2] = fmaf(a.x, b.z, acc[0][2]);
      acc[0][3] = fmaf(a.x, b.w, acc[0][3]);
      acc[1][0] = fmaf(a.y, b.x, acc[1][0]);
      acc[1][1] = fmaf(a.y, b.y, acc[1][1]);
      acc[1][2] = fmaf(a.y, b.z, acc[1][2]);
      acc[1][3] = fmaf(a.y, b.w, acc[1][3]);
      acc[2][0] = fmaf(a.z, b.x, acc[2][0]);
      acc[2][1] = fmaf(a.z, b.y, acc[2][1]);
      acc[2][2] = fmaf(a.z, b.z, acc[2][2]);
      acc[2][3] = fmaf(a.z, b.w, acc[2][3]);
      acc[3][0] = fmaf(a.w, b.x, acc[3][0]);
      acc[3][1] = fmaf(a.w, b.y, acc[3][1]);
      acc[3][2] = fmaf(a.w, b.z, acc[3][2]);
      acc[3][3] = fmaf(a.w, b.w, acc[3][3]);
    }
    __syncthreads();
  }
#pragma unroll
  for (int i = 0; i < 4; ++i) {
    int m = m0 + tm * 4 + i;
#pragma unroll
    for (int j = 0; j < 4; ++j) {
      int n = n0 + tn * 4 + j;
      if (m <= M)  // rows beyond the virtual row are scratch work
        Y[(size_t)m * N + n] = fmaxf(acc[i][j] + bias[n], 0.f);
    }
  }
}

// ---------------------------------------------------------------------------
// cdist: d[b][i][j] = || esrow(b,i) - etrow(b,j) ||_2
// Also accumulates per-batch fp64 sum via atomicAdd (order-nondeterministic,
// ~1e-15 rel noise; assignment downstream is scale-invariant — validated
// R21/R22/R23, absmax unchanged). R23-measured form (R24's LDS
// vectorization was neutral — reverted to the proven config).
// ---------------------------------------------------------------------------
__global__ __launch_bounds__(256) void cdist_kernel(
    const float* __restrict__ es, const float* __restrict__ et,
    const float* __restrict__ ev, float* __restrict__ d,
    double* __restrict__ sums_d) {
  const int b = blockIdx.z;
  const int i0 = blockIdx.x * 32;
  const int j0 = blockIdx.y * 32;
  __shared__ float sA[32][33];
  __shared__ float sB[32][33];
  const int tid = threadIdx.x;
  const int ty = tid / 16, tx = tid % 16;
  const int lr = tid / 8;
  const int lk4 = (tid % 8) * 4;
  const int gi = i0 + lr;
  const int gj = j0 + lr;
  const float* pa = (gi < NNODE) ? (es + ((size_t)b * NNODE + gi) * DIM) : ev;
  const float* pb = (gj < NNODE) ? (et + ((size_t)b * NNODE + gj) * DIM) : ev;
  float acc[2][2] = {};
  for (int k0 = 0; k0 < DIM; k0 += 32) {
    float4 av = *(const float4*)(pa + k0 + lk4);
    float4 bv = *(const float4*)(pb + k0 + lk4);
    sA[lr][lk4 + 0] = av.x; sA[lr][lk4 + 1] = av.y;
    sA[lr][lk4 + 2] = av.z; sA[lr][lk4 + 3] = av.w;
    sB[lr][lk4 + 0] = bv.x; sB[lr][lk4 + 1] = bv.y;
    sB[lr][lk4 + 2] = bv.z; sB[lr][lk4 + 3] = bv.w;
    __syncthreads();
#pragma unroll 8
    for (int k = 0; k < 32; ++k) {
      float a0 = sA[ty * 2 + 0][k], a1 = sA[ty * 2 + 1][k];
      float b0 = sB[tx * 2 + 0][k], b1 = sB[tx * 2 + 1][k];
      float d00 = a0 - b0, d01 = a0 - b1, d10 = a1 - b0, d11 = a1 - b1;
      acc[0][0] = fmaf(d00, d00, acc[0][0]);
      acc[0][1] = fmaf(d01, d01, acc[0][1]);
      acc[1][0] = fmaf(d10, d10, acc[1][0]);
      acc[1][1] = fmaf(d11, d11, acc[1][1]);
    }
    __syncthreads();
  }
  double psum = 0.0;
#pragma unroll
  for (int i = 0; i < 2; ++i) {
    int gi2 = i0 + ty * 2 + i;
#pragma unroll
    for (int j = 0; j < 2; ++j) {
      int gj2 = j0 + tx * 2 + j;
      if (gi2 < NP1 && gj2 < NP1) {
        const float s = sqrtf(acc[i][j]);
        d[(size_t)b * EDSZ + gi2 * NP1 + gj2] = s;
        psum += (double)s;
      }
    }
  }
  // per-wave reduce, one fp64 atomic per wave (4/block)
#pragma unroll
  for (int off = 32; off; off >>= 1) psum += __shfl_xor(psum, off);
  if ((tid & 63) == 0) atomicAdd(&sums_d[b], psum);
}

// ---------------------------------------------------------------------------
// Parallel normalize + A-zero (replaces sum_normalize AND the memset).
// Same per-element expression as the validated normalize:
// e = d / sumf * 16384.f.
// ---------------------------------------------------------------------------
__global__ __launch_bounds__(256) void normalize_zero(
    const float* __restrict__ d, const double* __restrict__ sums_d,
    float* __restrict__ edit, float* __restrict__ Aout) {
  const int b = blockIdx.x;
  const float sumf = (float)sums_d[b];
  const float nn = (float)(NNODE * NNODE);
  const float* db = d + (size_t)b * EDSZ;
  float* eb = edit + (size_t)b * EDSZ;
  float* Ab = Aout + (size_t)b * EDSZ;
  for (int idx = blockIdx.y * 256 + threadIdx.x; idx < EDSZ;
       idx += 256 * gridDim.y) {
    eb[idx] = db[idx] / sumf * nn;
    Ab[idx] = 0.f;
  }
}

// ---------------------------------------------------------------------------
// cross-lane helpers: 32-bit packed argmin on the VALU pipe.
// key = (f32 bits of nonneg value with low 7 mantissa bits replaced by col).
// Unsigned order == value order (to within 2^-17 rel; ties -> lowest col).
// Exact values recovered by readlane from the winner lane.
//
// Wave-min: the 6-step builtin update_dpp chain, FINAL. Three attempts to
// beat it all lost:
//   R14 hand-fused v_min_u32_dpp asm -> VALU->DPP hazard violation, hang.
//   R16 asm + embedded s_nop -> +49us (forced nops + asm sched barriers).
//   R22 readlane-tail (4 readlane + s_min tree) -> +18us (readlane-after-
//        VALU wait states + SALU chain beat by DPP's hazard-filled slots).
// Do not touch this function again.
// ---------------------------------------------------------------------------
__device__ __forceinline__ unsigned key_of(float m, int col) {
  return (__float_as_uint(m) & 0xFFFFFF80u) | (unsigned)col;
}

__device__ __forceinline__ float readlane_f32(float x, int lane) {
  return __uint_as_float(
      (unsigned)__builtin_amdgcn_readlane((int)__float_as_uint(x), lane));
}

template <int CTRL>
__device__ __forceinline__ unsigned dpp_umin_step(unsigned x) {
  const unsigned o = (unsigned)__builtin_amdgcn_update_dpp(
      (int)0xFFFFFFFFu, (int)x, CTRL, 0xf, 0xf, false);
  return o < x ? o : x;
}

// wave64 min-key; result broadcast (readlane 63).
__device__ __forceinline__ unsigned wave_umin_key(unsigned x) {
  x = dpp_umin_step<0x111>(x);
  x = dpp_umin_step<0x112>(x);
  x = dpp_umin_step<0x114>(x);
  x = dpp_umin_step<0x118>(x);
  x = dpp_umin_step<0x142>(x);
  x = dpp_umin_step<0x143>(x);
  return (unsigned)__builtin_amdgcn_readlane((int)x, 63);
}

// merged (min1,min2) reduction: one DPP chain carries a sorted pair (ARR).
template <int CTRL>
__device__ __forceinline__ void dpp_umin2_step(unsigned& m1, unsigned& m2) {
  const unsigned o1 = (unsigned)__builtin_amdgcn_update_dpp(
      (int)0xFFFFFFFFu, (int)m1, CTRL, 0xf, 0xf, false);
  const unsigned o2 = (unsigned)__builtin_amdgcn_update_dpp(
      (int)0xFFFFFFFFu, (int)m2, CTRL, 0xf, 0xf, false);
  const unsigned lo = m1 < o1 ? m1 : o1;
  const unsigned hi = m1 < o1 ? o1 : m1;
  const unsigned yo = m2 < o2 ? m2 : o2;
  m1 = lo;
  m2 = hi < yo ? hi : yo;
}

__device__ __forceinline__ void wave_umin2_key(unsigned a, unsigned b,
                                               unsigned& k1, unsigned& k2) {
  unsigned m1 = a < b ? a : b;
  unsigned m2 = a < b ? b : a;
  dpp_umin2_step<0x111>(m1, m2);
  dpp_umin2_step<0x112>(m1, m2);
  dpp_umin2_step<0x114>(m1, m2);
  dpp_umin2_step<0x118>(m1, m2);
  dpp_umin2_step<0x142>(m1, m2);
  dpp_umin2_step<0x143>(m1, m2);
  k1 = (unsigned)__builtin_amdgcn_readlane((int)m1, 63);
  k2 = (unsigned)__builtin_amdgcn_readlane((int)m2, 63);
}

// Broadcast element idx of a 128-entry distributed array (2 per lane).
__device__ __forceinline__ float bcast_pair_f(float a0, float a1, int idx) {
  const int l = idx >> 1;
  const float xa = readlane_f32(a0, l);
  const float xb = readlane_f32(a1, l);
  return (idx & 1) ? xb : xa;
}
__device__ __forceinline__ int bcast_pair_i(int a0, int a1, int idx) {
  const int l = idx >> 1;
  const int xa = __builtin_amdgcn_readlane(a0, l);
  const int xb = __builtin_amdgcn_readlane(a1, l);
  return (idx & 1) ? xb : xa;
}

// ---------------------------------------------------------------------------
// LSAPE collapsed to a dense 128x128 LSAP, LAPJV pipeline. ONE WAVE per
// batch, lane owns 2 columns. R20-validated kernel VERBATIM (497us):
// stage D with fminf only, 6-step DPP argmin, col reduction -> greedy ->
// reduction transfer -> adaptive multi-pass ARR -> exact SAP. Scan schedule
// is compiler-optimal (R15/R16/R22); the only lever that has ever moved
// this kernel is SCAN COUNT (R17, R20). GOLDEN — do not touch.
// ---------------------------------------------------------------------------
__global__ __launch_bounds__(64) void lsap_kernel(
    const float* __restrict__ edit, float* __restrict__ Aout,
    float* __restrict__ geds) {
  const int b = blockIdx.x;
  const float* ec = edit + (size_t)b * EDSZ;
  float* A = Aout + (size_t)b * EDSZ;
  const int lane = threadIdx.x;
  const int cbase = lane * 2;  // first owned column (0-based), 2 per lane

  __shared__ float D[NNODE * NNODE];  // 64 KB dense collapsed cost

  // stage D = min(sub, del+ins); coalesced global reads (L2-resident)
  for (int idx = lane; idx < NNODE * NNODE; idx += 64) {
    const int i = idx >> 7, j = idx & 127;
    const float sub = ec[i * NP1 + j];
    const float di = ec[i * NP1 + NNODE] + ec[NNODE * NP1 + j];
    D[idx] = fminf(sub, di);
  }
  __syncthreads();

  const float* Dl = D + cbase;  // lane-local column-pair base

  // per-lane state: 2 columns (v, minv, way, p) + 2 rows (u, x=row->col+1)
  float u0 = 0.f, u1 = 0.f;
  float v0 = 0.f, v1 = 0.f;
  float m0, m1;
  int w0 = 0, w1 = 0;
  int p0 = 0, p1 = 0;
  int x0 = 0, x1 = 0;

  // ---------------- Phase 1: column reduction on dense D ----------------
  int y0 = 0, y1 = 0;
  {
    float c0 = BIGF, c1 = BIGF;
    for (int r = 0; r < NNODE; ++r) {
      const float2 f = *(const float2*)(Dl + (r << 7));
      if (f.x < c0) { c0 = f.x; y0 = r; }
      if (f.y < c1) { c1 = f.y; y1 = r; }
    }
    v0 = c0; v1 = c1;
  }

  // Greedy conflict-free assignment (wave-uniform scalar walk over columns).
  unsigned long long ra0 = 0, ra1 = 0;  // assigned-row bits (0..63, 64..127)
  for (int j = 0; j < NNODE; ++j) {
    const int i1 = bcast_pair_i(y0, y1, j);
    const int bit = i1 & 63;
    const unsigned long long msk = (i1 < 64) ? ra0 : ra1;
    if (!((msk >> bit) & 1ull)) {
      if (i1 < 64) ra0 |= 1ull << bit; else ra1 |= 1ull << bit;
      const bool oj = lane == (j >> 1);
      p0 = (oj && !(j & 1)) ? i1 + 1 : p0;
      p1 = (oj &&  (j & 1)) ? i1 + 1 : p1;
      const bool oi = lane == (i1 >> 1);
      x0 = (oi && !(i1 & 1)) ? j + 1 : x0;
      x1 = (oi &&  (i1 & 1)) ? j + 1 : x1;
    }
  }

  // ---------------- Phase 1r: reduction transfer ----------------
  for (int ii = 0; ii < NNODE; ++ii) {
    const float2 f = *(const float2*)(Dl + (ii << 7));
    const int xj = bcast_pair_i(x0, x1, ii);
    if (xj == 0) continue;
    const int j1 = xj - 1;
    float r0 = fmaxf(f.x - v0, 0.f);
    float r1 = fmaxf(f.y - v1, 0.f);
    if (cbase + 0 == j1) r0 = BIGF;
    if (cbase + 1 == j1) r1 = BIGF;
    const unsigned ka = key_of(r0, cbase + 0);
    const unsigned kb = key_of(r1, cbase + 1);
    const unsigned kmin = wave_umin_key(ka < kb ? ka : kb);
    const int jm = (int)(kmin & 127u);
    const float umin = bcast_pair_f(r0, r1, jm);
    const bool ov = lane == (j1 >> 1);
    v0 = (ov && !(j1 & 1)) ? v0 - umin : v0;
    v1 = (ov &&  (j1 & 1)) ? v1 - umin : v1;
    const bool ou = lane == (ii >> 1);
    u0 = (ou && !(ii & 1)) ? umin : u0;
    u1 = (ou &&  (ii & 1)) ? umin : u1;
  }

  // ---------------- Phase 1.5: adaptive multi-pass ARR ----------------
  // Ordered passes over the pass-start free list; displaced rows wait for
  // the next pass, keep their duals. Stop when a pass converts nothing
  // net, cap 8 passes. (R20 win: ARR step ~400cy vs phase-2 row ~40k cy.)
  {
    int nfree_prev =
        NNODE - __builtin_popcountll(ra0) - __builtin_popcountll(ra1);
    for (int pass = 0; pass < 8 && nfree_prev; ++pass) {
      unsigned long long todo0 = ~ra0, todo1 = ~ra1;
      while (todo0 | todo1) {
        int i;
        if (todo0) { i = __builtin_ctzll(todo0); todo0 &= todo0 - 1ull; }
        else       { i = 64 + __builtin_ctzll(todo1); todo1 &= todo1 - 1ull; }

        const float2 f = *(const float2*)(Dl + (i << 7));
        const float r0 = fmaxf(f.x - v0, 0.f);
        const float r1 = fmaxf(f.y - v1, 0.f);
        unsigned k1, k2;
        wave_umin2_key(key_of(r0, cbase + 0), key_of(r1, cbase + 1), k1, k2);
        const int j1 = (int)(k1 & 127u), j2 = (int)(k2 & 127u);
        const float u1v = bcast_pair_f(r0, r1, j1);
        const float u2v = bcast_pair_f(r0, r1, j2);

        int jt = j1;
        int i1 = bcast_pair_i(p0, p1, j1);
        if (u1v < u2v) {
          const float dv = u2v - u1v;
          const bool ov = lane == (j1 >> 1);
          v0 = (ov && !(j1 & 1)) ? v0 - dv : v0;
          v1 = (ov &&  (j1 & 1)) ? v1 - dv : v1;
        } else if (i1 != 0) {
          jt = j2;
          i1 = bcast_pair_i(p0, p1, j2);
        }
        // assign i -> jt with exact u[i] = u2v (feasible + tight)
        {
          const bool oj = lane == (jt >> 1);
          p0 = (oj && !(jt & 1)) ? i + 1 : p0;
          p1 = (oj &&  (jt & 1)) ? i + 1 : p1;
          const bool oi = lane == (i >> 1);
          u0 = (oi && !(i & 1)) ? u2v : u0;
          u1 = (oi &&  (i & 1)) ? u2v : u1;
        }
        if (i < 64) ra0 |= 1ull << i; else ra1 |= 1ull << (i - 64);
        if (i1 != 0) {
          const int rr = i1 - 1;
          if (rr < 64) ra0 &= ~(1ull << rr); else ra1 &= ~(1ull << (rr - 64));
          // displaced row KEEPS its dual u (feasible: v only decreases)
        }
      }
      const int nfree_now =
          NNODE - __builtin_popcountll(ra0) - __builtin_popcountll(ra1);
      if (nfree_now == nfree_prev) break;  // pass converted nothing net
      nfree_prev = nfree_now;
    }
  }

  // ---------------- Phase 2: SAP for each remaining free row ----------------
  for (int ii = 0; ii < NNODE; ++ii) {
    const unsigned long long amsk = (ii < 64) ? ra0 : ra1;
    if ((amsk >> (ii & 63)) & 1ull) continue;  // assigned in phase 1/1.5
    const int i = ii + 1;

    unsigned cused = 0, rused = 0;
    m0 = m1 = BIGF;
    int j0 = 0;       // current column (0 = dummy start)
    int i0 = i;       // p[0] = i
    for (int guard = 0; guard <= NNODE; ++guard) {
      // --- dense cost row: issue the LDS read first (longest latency) ---
      const float2 f = *(const float2*)(Dl + ((i0 - 1) << 7));

      // --- broadcast u[i0] (parallel readlanes + scalar select) ---
      const float u_i0 = bcast_pair_f(u0, u1, i0 - 1);

      // --- mark used: column j0 (skip dummy col 0) and row i0, branchless ---
      {
        const int jm1 = j0 - 1;
        const bool oc = (j0 > 0) && (lane == (jm1 >> 1));
        const bool c0m = oc && !(jm1 & 1);
        const bool c1m = oc &&  (jm1 & 1);
        cused |= c0m ? 1u : 0u;
        cused |= c1m ? 2u : 0u;
        m0 = c0m ? BIGF : m0;
        m1 = c1m ? BIGF : m1;
        const int im1 = i0 - 1;
        const bool orow = lane == (im1 >> 1);
        rused |= (orow && !(im1 & 1)) ? 1u : 0u;
        rused |= (orow &&  (im1 & 1)) ? 2u : 0u;
      }

      // --- relax free columns; clamp >=0 keeps key ordering sound ---
      {
        const float cur0 = fmaxf(f.x - u_i0 - v0, 0.f);
        const bool up0 = !(cused & 1u) && (cur0 < m0);
        m0 = up0 ? cur0 : m0;
        w0 = up0 ? j0 : w0;
        const float cur1 = fmaxf(f.y - u_i0 - v1, 0.f);
        const bool up1 = !(cused & 2u) && (cur1 < m1);
        m1 = up1 ? cur1 : m1;
        w1 = up1 ? j0 : w1;
      }

      // --- 32-bit key argmin; exact delta via winner readlane ---
      const unsigned ka = key_of(m0, cbase + 0);
      const unsigned kb = key_of(m1, cbase + 1);
      const unsigned kmin = wave_umin_key(ka < kb ? ka : kb);
      const int jcol = (int)(kmin & 127u);
      const float delta = bcast_pair_f(m0, m1, jcol);
      const int pj1 = bcast_pair_i(p0, p1, jcol);

      // --- dual updates (registers only, branchless) ---
      {
        const bool used0 = (cused & 1u) != 0;
        const bool used1 = (cused & 2u) != 0;
        v0 = used0 ? v0 - delta : v0;
        v1 = used1 ? v1 - delta : v1;
        m0 = used0 ? m0 : fmaxf(m0 - delta, 0.f);
        m1 = used1 ? m1 : fmaxf(m1 - delta, 0.f);
        u0 = (rused & 1u) ? u0 + delta : u0;
        u1 = (rused & 2u) ? u1 + delta : u1;
      }

      // --- next (or break on free column) ---
      j0 = jcol + 1;
      if (pj1 == 0) break;
      i0 = pj1;
    }

    // --- augment along way[] chain (uniform walk via readlane) ---
    int jc = j0;
    while (jc != 0) {
      const int jp = bcast_pair_i(w0, w1, jc - 1);
      const int js = (jp == 0) ? 1 : jp;  // safe index for speculative readlane
      const int pvr = bcast_pair_i(p0, p1, js - 1);
      const int pv = (jp == 0) ? i : pvr;
      const bool oc = lane == ((jc - 1) >> 1);
      p0 = (oc && !((jc - 1) & 1)) ? pv : p0;
      p1 = (oc &&  ((jc - 1) & 1)) ? pv : p1;
      jc = jp;
    }
  }

  // --- emit A and geds: column j assigned row p[j+1]-1; re-split branches ---
  double contrib = 0.0;
  {
    const int pr[2] = {p0, p1};
#pragma unroll
    for (int q = 0; q < 2; ++q) {
      const int j = cbase + q;
      const int i = pr[q] - 1;
      const float sub = ec[i * NP1 + j];
      const float di = ec[i * NP1 + NNODE] + ec[NNODE * NP1 + j];
      if (sub < di) {
        A[i * NP1 + j] = 1.f;
        contrib += (double)sub;
      } else {
        A[i * NP1 + NNODE] = 1.f;    // delete row i
        A[NNODE * NP1 + j] = 1.f;    // insert col j
        contrib += (double)di;
      }
    }
  }
#pragma unroll
  for (int off = 32; off; off >>= 1) contrib += __shfl_xor(contrib, off);
  if (lane == 0) geds[b] = (float)(contrib / 256.0);
}

// ---------------------------------------------------------------------------
// launch: 5 dispatches — gemm x2, cdist(+sum), normalize_zero, lsap
// ---------------------------------------------------------------------------
extern "C" void kernel_launch(void* const* d_in, const int* in_sizes, int n_in,
                              void* d_out, int out_size, void* d_ws, size_t ws_size,
                              hipStream_t stream) {
  const float* x_s  = (const float*)d_in[0];
  const float* x_t  = (const float*)d_in[1];
  const float* W1   = (const float*)d_in[2];
  const float* b1   = (const float*)d_in[3];
  const float* W2   = (const float*)d_in[4];
  const float* b2   = (const float*)d_in[5];
  const float* virt = (const float*)d_in[6];

  const int M = BATCH * NNODE;  // 2048

  // h_s / e_s carry one extra row (the virtual node) at index M.
  float* ws    = (float*)d_ws;
  float* h_s   = ws;                                   // (M+1) x DIM
  float* h_t   = h_s + ((size_t)M + 1) * DIM;          //  M    x DIM
  float* e_s   = h_t + (size_t)M * DIM;                // (M+1) x DIM
  float* e_t   = e_s + ((size_t)M + 1) * DIM;          //  M    x DIM
  float* d_raw = e_t + (size_t)M * DIM;                // 16*16641
  double* sums_d = (double*)(d_raw + (size_t)BATCH * EDSZ);  // 16 fp64

  float* Aout = (float*)d_out;
  float* edit = Aout + (size_t)BATCH * EDSZ;
  float* geds = edit + (size_t)BATCH * EDSZ;

  // 33rd x-tile carries the virtual node through both layers (z==0 only)
  dim3 gblk(M / 64 + 1, DIM / 64, 2);  // (33, 8, 2)
  gemm2_nt_relu<<<gblk, 256, 0, stream>>>(x_s, x_t, virt, W1, b1,
                                          h_s, h_t, sums_d, M, DIM, DIM);
  gemm2_nt_relu<<<gblk, 256, 0, stream>>>(h_s, h_t, h_s + (size_t)M * DIM,
                                          W2, b2, e_s, e_t, nullptr,
                                          M, DIM, DIM);

  const float* e_v = e_s + (size_t)M * DIM;
  cdist_kernel<<<dim3(5, 5, BATCH), 256, 0, stream>>>(e_s, e_t, e_v, d_raw,
                                                      sums_d);
  normalize_zero<<<dim3(BATCH, 4), 256, 0, stream>>>(d_raw, sums_d, edit, Aout);
  lsap_kernel<<<BATCH, 64, 0, stream>>>(edit, Aout, geds);
}